// Round 13
// baseline (546.052 us; speedup 1.0000x reference)
//
#include <hip/hip_runtime.h>

#define NRES 384
#define CZ 128
#define NH 4
#define CH 32
#define NN (NRES * NRES)
#define NNCZ ((size_t)NN * CZ)

typedef unsigned short u16;
typedef __attribute__((ext_vector_type(4))) unsigned short us4;
typedef __attribute__((ext_vector_type(8))) unsigned short us8;
typedef __attribute__((ext_vector_type(8))) short s8;   // 8 bf16 = MFMA A/B frag
typedef __attribute__((ext_vector_type(4))) float f4;   // MFMA C/D frag

__device__ __forceinline__ float bf2f(u16 u) {
  return __uint_as_float(((unsigned)u) << 16);
}
__device__ __forceinline__ u16 f2bf(float f) {
  unsigned u = __float_as_uint(f);
  u += 0x7fffu + ((u >> 16) & 1u);  // RTNE
  return (u16)(u >> 16);
}

template<bool F32>
__device__ __forceinline__ float ld1(const void* p, size_t i) {
  if constexpr (F32) return ((const float*)p)[i];
  else return bf2f(((const u16*)p)[i]);
}

template<bool F32>
__device__ __forceinline__ void ld4v(const void* p, size_t i, float o[4]) {
  if constexpr (F32) {
    const float4 a = *(const float4*)((const float*)p + i);
    o[0] = a.x; o[1] = a.y; o[2] = a.z; o[3] = a.w;
  } else {
    const us4 v = *(const us4*)((const u16*)p + i);
    #pragma unroll
    for (int u = 0; u < 4; ++u) o[u] = bf2f(v[u]);
  }
}

template<bool F32>
__device__ __forceinline__ void ld8(const void* p, size_t i, float o[8]) {
  if constexpr (F32) {
    const float4 a = *(const float4*)((const float*)p + i);
    const float4 b = *(const float4*)((const float*)p + i + 4);
    o[0] = a.x; o[1] = a.y; o[2] = a.z; o[3] = a.w;
    o[4] = b.x; o[5] = b.y; o[6] = b.z; o[7] = b.w;
  } else {
    const us8 v = *(const us8*)((const u16*)p + i);
    #pragma unroll
    for (int u = 0; u < 8; ++u) o[u] = bf2f(v[u]);
  }
}

// ---------------------------------------------------------------------------
// Probe: decide input dtype from z's exponent-bit statistics.
// ---------------------------------------------------------------------------
__global__ void k_probe(const u16* __restrict__ z, int* __restrict__ flag) {
  int weird = 0;
  for (int i = threadIdx.x; i < 256; i += 64) {
    const int e = (z[i] >> 7) & 0xFF;
    if (e < 0x70 || e > 0x8F) weird++;
  }
  #pragma unroll
  for (int m = 1; m < 64; m <<= 1) weird += __shfl_xor(weird, m, 64);
  if (threadIdx.x == 0) *flag = (weird >= 16) ? 1 : 0;
}

// ---------------------------------------------------------------------------
// K0: one-time weight repack into A-fragment order (bf16, workspace).
//   elem (m=outch, k=c) at [ks*4096 + (((m>>4)*4+qq)*16+(m&15))*8 + j],
//   c = ks*32 + qq*8 + j.
//   Arrays: 0=wq (q-scale folded), 1=wk, 2=wv, 3=wg, 4=wo,
//           5=w_bias padded 4->16 outch (zeros above h=3).
// ---------------------------------------------------------------------------
template<bool F32>
__global__ void k_repack(const void* __restrict__ w0, const void* __restrict__ w1,
                         const void* __restrict__ w2, const void* __restrict__ w3,
                         const void* __restrict__ w4p, const void* __restrict__ w5b,
                         u16* __restrict__ dst, const int* __restrict__ flag) {
  if ((*flag != 0) != F32) return;
  const int a = blockIdx.x;   // 0..5
  u16* d = dst + (size_t)a * 16384;
  const int t = threadIdx.x;
  if (a == 5) {
    #pragma unroll
    for (int it = 0; it < 16; ++it) {
      const int c = (t >> 5) + it * 8;
      const int m0 = (t & 31) * 4;
      float w4[4] = {0.f, 0.f, 0.f, 0.f};
      if (m0 == 0) ld4v<F32>(w5b, (size_t)c * NH, w4);   // wbias[c][0..3]
      const int ks = c >> 5, qq = (c >> 3) & 3, j = c & 7;
      #pragma unroll
      for (int mm = 0; mm < 4; ++mm) {
        const int m = m0 + mm;
        d[ks * 4096 + (((m >> 4) * 4 + qq) * 16 + (m & 15)) * 8 + j] = f2bf(w4[mm]);
      }
    }
    return;
  }
  const void* W = (a == 0) ? w0 : (a == 1) ? w1 : (a == 2) ? w2 : (a == 3) ? w3 : w4p;
  const float scl = (a == 0) ? 0.17677669529663687f : 1.0f;   // CH^-0.5 folded into wq
  #pragma unroll
  for (int it = 0; it < 16; ++it) {
    const int c = (t >> 5) + it * 8;
    const int m0 = (t & 31) * 4;
    float w4[4];
    ld4v<F32>(W, (size_t)c * CZ + m0, w4);
    const int ks = c >> 5, qq = (c >> 3) & 3, j = c & 7;
    #pragma unroll
    for (int mm = 0; mm < 4; ++mm) {
      const int m = m0 + mm;
      d[ks * 4096 + (((m >> 4) * 4 + qq) * 16 + (m & 15)) * 8 + j] = f2bf(w4[mm] * scl);
    }
  }
}

// ---------------------------------------------------------------------------
// K1: LayerNorm + MFMA projections + tri_bias (transposed out).
//   R13: launch_bounds (256,2)->(256,3). LDS 34816 B allows 4 blocks/CU but
//   the (256,2) reg cap (256) let the allocator pin us at 2 blocks/CU
//   (2.25 dispatch rounds, half-empty tail). Live set ~110-130 regs fits the
//   (256,3) cap of 170 with headroom (same config that worked on k_attn, R7).
//   tri_bias via MFMA; q-scale folded into repacked wq. LDS = znl only.
// ---------------------------------------------------------------------------
template<bool F32>
__global__ __launch_bounds__(256, 3) void k_ln_proj(
    const void* __restrict__ z, const void* __restrict__ gma, const void* __restrict__ bta,
    const u16* __restrict__ wrep, const void* __restrict__ bg,
    u16* __restrict__ qb, u16* __restrict__ kb, u16* __restrict__ vb, u16* __restrict__ gb,
    float* __restrict__ triT, const int* __restrict__ flag)
{
  if ((*flag != 0) != F32) return;
  __shared__ __align__(16) u16 znl[128 * 136];   // 34816 B (only LDS)
  const int t = threadIdx.x;
  const int lane = t & 63;
  const int wid = t >> 6;
  const int n16 = lane & 15;
  const int quad = lane >> 4;   // also LN row-group
  const int rowBase = blockIdx.x * 128;

  // ---- LayerNorm ----
  const int c0 = n16 * 8;
  float g8[8], b8[8];
  ld8<F32>(gma, c0, g8);
  ld8<F32>(bta, c0, b8);
  for (int it = 0; it < 8; ++it) {
    const int rl = wid * 32 + it * 4 + quad;
    float x[8];
    ld8<F32>(z, (size_t)(rowBase + rl) * CZ + c0, x);
    float s = 0.f, q2 = 0.f;
    #pragma unroll
    for (int u = 0; u < 8; ++u) { s += x[u]; q2 += x[u] * x[u]; }
    #pragma unroll
    for (int m = 1; m < 16; m <<= 1) {
      s  += __shfl_xor(s, m, 64);
      q2 += __shfl_xor(q2, m, 64);
    }
    const float mu = s * (1.0f / CZ);
    const float rs = rsqrtf(q2 * (1.0f / CZ) - mu * mu + 1e-5f);
    us8 o;
    #pragma unroll
    for (int u = 0; u < 8; ++u) o[u] = f2bf((x[u] - mu) * rs * g8[u] + b8[u]);
    *(us8*)&znl[rl * 136 + c0] = o;
  }
  __syncthreads();

  // ---- tri_bias via MFMA: D = w_bias^T(padded) @ zn^T, rows 0..3 = heads ----
  {
    const u16* WTb = wrep + (size_t)5 * 16384;
    f4 acc2[2];
    acc2[0] = f4{0.f, 0.f, 0.f, 0.f};
    acc2[1] = f4{0.f, 0.f, 0.f, 0.f};
    #pragma unroll
    for (int ks = 0; ks < 4; ++ks) {
      const s8 ab = *(const s8*)&WTb[ks * 4096 + (quad * 16 + n16) * 8];  // mt=0
      #pragma unroll
      for (int i = 0; i < 2; ++i) {
        const s8 b = *(const s8*)&znl[((wid * 2 + i) * 16 + n16) * 136 + ks * 32 + quad * 8];
        acc2[i] = __builtin_amdgcn_mfma_f32_16x16x32_bf16(ab, b, acc2[i], 0, 0, 0);
      }
    }
    if (quad == 0) {
      #pragma unroll
      for (int i = 0; i < 2; ++i) {
        const int P = rowBase + (wid * 2 + i) * 16 + n16;
        const int aI = P / NRES, bI = P % NRES;   // pair (qrow=aI, key=bI)
        #pragma unroll
        for (int r = 0; r < 4; ++r)
          triT[(size_t)r * NN + (size_t)bI * NRES + aI] = acc2[i][r];
      }
    }
  }

  // ---- 4 projection GEMMs, weights from repacked global ----
  for (int arr = 0; arr < 4; ++arr) {
    const u16* WTg = wrep + (size_t)arr * 16384;

    f4 acc[2][8];
    #pragma unroll
    for (int i = 0; i < 2; ++i)
      #pragma unroll
      for (int nt = 0; nt < 8; ++nt) acc[i][nt] = f4{0.f, 0.f, 0.f, 0.f};

    #pragma unroll
    for (int ks = 0; ks < 4; ++ks) {
      s8 a[2], b[8];
      #pragma unroll
      for (int i = 0; i < 2; ++i)
        a[i] = *(const s8*)&WTg[ks * 4096 + (((wid * 2 + i) * 4 + quad) * 16 + n16) * 8];
      #pragma unroll
      for (int nt = 0; nt < 8; ++nt)
        b[nt] = *(const s8*)&znl[(nt * 16 + n16) * 136 + ks * 32 + quad * 8];
      #pragma unroll
      for (int i = 0; i < 2; ++i)
        #pragma unroll
        for (int nt = 0; nt < 8; ++nt)
          acc[i][nt] = __builtin_amdgcn_mfma_f32_16x16x32_bf16(a[i], b[nt], acc[i][nt], 0, 0, 0);
    }

    u16* dstb = (arr == 0) ? qb : (arr == 1) ? kb : (arr == 2) ? vb : gb;
    #pragma unroll
    for (int i = 0; i < 2; ++i) {
      const int mt = wid * 2 + i;
      const int och0 = mt * 16 + quad * 4;
      float e4[4];
      if (arr == 3) ld4v<F32>(bg, och0, e4);
      #pragma unroll
      for (int nt = 0; nt < 8; ++nt) {
        us4 o;
        #pragma unroll
        for (int r = 0; r < 4; ++r) {
          float v = acc[i][nt][r];
          if (arr == 3) v = 1.0f / (1.0f + __expf(-(v + e4[r])));
          o[r] = f2bf(v);
        }
        *(us4*)&dstb[(size_t)(rowBase + nt * 16 + n16) * CZ + och0] = o;
      }
    }
  }
}

// ---------------------------------------------------------------------------
// K2: MFMA attention (exact R4 config — best measured: 206us, 84 VGPR,
// zero spill). Online softmax, 2 q-tiles/wave, 64-key chunks, K reg-prefetch.
// Lesson from R5-R8: live set must stay < ~85 VGPRs or hipcc spills rather
// than allocating more. Do not add register state to this kernel.
//   LDS: 24576 (VB) + 10240 (Pch[4][2]) + 1536 (mbL) = 36352 B.
// ---------------------------------------------------------------------------
template<bool F32>
__global__ __launch_bounds__(256, 3) void k_attn(
    const u16* __restrict__ qb, const u16* __restrict__ kb, const u16* __restrict__ vb,
    const u16* __restrict__ gb, const float* __restrict__ triT, const void* __restrict__ msk,
    u16* __restrict__ ogb, const int* __restrict__ flag)
{
  if ((*flag != 0) != F32) return;
  __shared__ __align__(16) u16 VB[12 * 4 * 32 * 8];  // [sub32][quad][d][j], key-permuted
  __shared__ __align__(16) u16 Pch[4][2][16 * 40];   // per-wave, per-qtile P chunk
  __shared__ __align__(16) float mbL[NRES];          // mask bias per key
  const int t = threadIdx.x;
  const int i = blockIdx.x >> 2;
  const int h = blockIdx.x & 3;
  const size_t base_i = (size_t)i * NRES;

  #pragma unroll
  for (int it = 0; it < 12; ++it) {
    const int idx = t + it * 256;
    const int kk = idx >> 3;
    const int d0 = (idx & 7) * 4;
    const us4 vv = *(const us4*)&vb[(base_i + kk) * CZ + h * CH + d0];
    const int cc2 = kk >> 5;
    const int kap = kk & 31;
    const int p = 2 * (kap & 15) + (kap >> 4);   // key-interleave position
    u16* vdst = &VB[((cc2 * 4 + (p >> 3)) * 32 + d0) * 8 + (p & 7)];
    vdst[0] = vv[0]; vdst[8] = vv[1]; vdst[16] = vv[2]; vdst[24] = vv[3];
  }
  for (int idx = t; idx < NRES; idx += 256)
    mbL[idx] = 1.0e9f * (ld1<F32>(msk, base_i + idx) - 1.0f);
  __syncthreads();

  const int wid = t >> 6;
  const int lane = t & 63;
  const int n = lane & 15;
  const int quad = lane >> 4;
  const float* trih = triT + (size_t)h * NN;
  u16* pbA = &Pch[wid][0][0];
  u16* pbB = &Pch[wid][1][0];

  for (int pr = wid; pr < 12; pr += 4) {
    const int jrowA = pr * 32;
    const int jrowB = jrowA + 16;
    const s8 aqA = *(const s8*)&qb[(base_i + jrowA + n) * CZ + h * CH + quad * 8];
    const s8 aqB = *(const s8*)&qb[(base_i + jrowB + n) * CZ + h * CH + quad * 8];

    f4 O0A = {0.f,0.f,0.f,0.f}, O1A = {0.f,0.f,0.f,0.f};
    f4 O0B = {0.f,0.f,0.f,0.f}, O1B = {0.f,0.f,0.f,0.f};
    f4 lA = {0.f,0.f,0.f,0.f}, lB = {0.f,0.f,0.f,0.f};
    f4 mA = {-1.0e30f,-1.0e30f,-1.0e30f,-1.0e30f};
    f4 mB = {-1.0e30f,-1.0e30f,-1.0e30f,-1.0e30f};

    // preload K chunk 0
    s8 bk[4];
    #pragma unroll
    for (int u = 0; u < 4; ++u)
      bk[u] = *(const s8*)&kb[(base_i + u * 16 + n) * CZ + h * CH + quad * 8];

    #pragma unroll 1
    for (int cc = 0; cc < 6; ++cc) {
      // ---- QK^T for 4 key tiles (64 keys), both q-tiles ----
      f4 SA[4], SB[4];
      #pragma unroll
      for (int u = 0; u < 4; ++u) {
        const f4 z4 = {0.f, 0.f, 0.f, 0.f};
        SA[u] = __builtin_amdgcn_mfma_f32_16x16x32_bf16(aqA, bk[u], z4, 0, 0, 0);
        SB[u] = __builtin_amdgcn_mfma_f32_16x16x32_bf16(aqB, bk[u], z4, 0, 0, 0);
      }
      // ---- prefetch next chunk's K (hidden under softmax+PV) ----
      if (cc < 5) {
        #pragma unroll
        for (int u = 0; u < 4; ++u)
          bk[u] = *(const s8*)&kb[(base_i + ((cc + 1) * 4 + u) * 16 + n) * CZ + h * CH + quad * 8];
      }
      // ---- bias: tri (f32 float4, paired lines) + mask (LDS broadcast) ----
      #pragma unroll
      for (int u = 0; u < 4; ++u) {
        const int tt = cc * 4 + u;
        const float mbv = mbL[tt * 16 + n];
        const size_t trow = (size_t)(tt * 16 + n) * NRES;
        const float4 tA = *(const float4*)&trih[trow + jrowA + quad * 4];
        const float4 tB = *(const float4*)&trih[trow + jrowB + quad * 4];
        SA[u][0] += tA.x + mbv; SA[u][1] += tA.y + mbv;
        SA[u][2] += tA.z + mbv; SA[u][3] += tA.w + mbv;
        SB[u][0] += tB.x + mbv; SB[u][1] += tB.y + mbv;
        SB[u][2] += tB.z + mbv; SB[u][3] += tB.w + mbv;
      }
      // ---- online softmax: chunk max, rescale running state ----
      f4 mxA = SA[0], mxB = SB[0];
      #pragma unroll
      for (int u = 1; u < 4; ++u) {
        #pragma unroll
        for (int r = 0; r < 4; ++r) {
          mxA[r] = fmaxf(mxA[r], SA[u][r]);
          mxB[r] = fmaxf(mxB[r], SB[u][r]);
        }
      }
      #pragma unroll
      for (int sft = 1; sft < 16; sft <<= 1) {
        #pragma unroll
        for (int r = 0; r < 4; ++r) {
          mxA[r] = fmaxf(mxA[r], __shfl_xor(mxA[r], sft, 64));
          mxB[r] = fmaxf(mxB[r], __shfl_xor(mxB[r], sft, 64));
        }
      }
      #pragma unroll
      for (int r = 0; r < 4; ++r) {
        const float mnA = fmaxf(mA[r], mxA[r]);
        const float scA = __expf(mA[r] - mnA);
        mA[r] = mnA;
        O0A[r] *= scA; O1A[r] *= scA; lA[r] *= scA;
        const float mnB = fmaxf(mB[r], mxB[r]);
        const float scB = __expf(mB[r] - mnB);
        mB[r] = mnB;
        O0B[r] *= scB; O1B[r] *= scB; lB[r] *= scB;
      }
      #pragma unroll
      for (int u = 0; u < 4; ++u) {
        #pragma unroll
        for (int r = 0; r < 4; ++r) {
          SA[u][r] = __expf(SA[u][r] - mA[r]);
          lA[r] += SA[u][r];
          SB[u][r] = __expf(SB[u][r] - mB[r]);
          lB[r] += SB[u][r];
        }
      }
      // ---- P pack -> LDS -> PV, 2 sub-chunks of 32 keys; V frags shared ----
      #pragma unroll
      for (int s = 0; s < 2; ++s) {
        #pragma unroll
        for (int r = 0; r < 4; ++r) {
          const unsigned wA = (unsigned)f2bf(SA[2 * s][r]) |
                              ((unsigned)f2bf(SA[2 * s + 1][r]) << 16);
          *(unsigned*)&pbA[(quad * 4 + r) * 40 + n * 2] = wA;
          const unsigned wB = (unsigned)f2bf(SB[2 * s][r]) |
                              ((unsigned)f2bf(SB[2 * s + 1][r]) << 16);
          *(unsigned*)&pbB[(quad * 4 + r) * 40 + n * 2] = wB;
        }
        const int C = cc * 2 + s;
        const s8 apA = *(const s8*)&pbA[n * 40 + quad * 8];
        const s8 apB = *(const s8*)&pbB[n * 40 + quad * 8];
        const s8 bv0 = *(const s8*)&VB[((C * 4 + quad) * 32 + n) * 8];
        const s8 bv1 = *(const s8*)&VB[((C * 4 + quad) * 32 + 16 + n) * 8];
        O0A = __builtin_amdgcn_mfma_f32_16x16x32_bf16(apA, bv0, O0A, 0, 0, 0);
        O1A = __builtin_amdgcn_mfma_f32_16x16x32_bf16(apA, bv1, O1A, 0, 0, 0);
        O0B = __builtin_amdgcn_mfma_f32_16x16x32_bf16(apB, bv0, O0B, 0, 0, 0);
        O1B = __builtin_amdgcn_mfma_f32_16x16x32_bf16(apB, bv1, O1B, 0, 0, 0);
      }
    }

    // ---- finish: sum-reduce over the 16-lane key axis, gate, store ----
    f4 sA = lA, sB = lB;
    #pragma unroll
    for (int sft = 1; sft < 16; sft <<= 1) {
      #pragma unroll
      for (int r = 0; r < 4; ++r) {
        sA[r] += __shfl_xor(sA[r], sft, 64);
        sB[r] += __shfl_xor(sB[r], sft, 64);
      }
    }
    #pragma unroll
    for (int r = 0; r < 4; ++r) {
      const float ivA = 1.0f / sA[r];
      const size_t rowA = (base_i + jrowA + quad * 4 + r) * CZ + h * CH;
      const float gA0 = bf2f(gb[rowA + n]);
      const float gA1 = bf2f(gb[rowA + 16 + n]);
      ogb[rowA + n]      = f2bf(O0A[r] * ivA * gA0);
      ogb[rowA + 16 + n] = f2bf(O1A[r] * ivA * gA1);
      const float ivB = 1.0f / sB[r];
      const size_t rowB = (base_i + jrowB + quad * 4 + r) * CZ + h * CH;
      const float gB0 = bf2f(gb[rowB + n]);
      const float gB1 = bf2f(gb[rowB + 16 + n]);
      ogb[rowB + n]      = f2bf(O0B[r] * ivB * gB0);
      ogb[rowB + 16 + n] = f2bf(O1B[r] * ivB * gB1);
    }
  }
}

// ---------------------------------------------------------------------------
// K3: out = (o*g) @ w_o + b_o.
//   R13: launch_bounds (256,2)->(256,3) — same occupancy fix as K1.
//   w_o pre-repacked (wrep+4*16384). LDS = ol only 34816 B.
// ---------------------------------------------------------------------------
template<bool F32>
__global__ __launch_bounds__(256, 3) void k_out(
    const u16* __restrict__ og, const u16* __restrict__ wrep, const void* __restrict__ bo,
    void* __restrict__ outp, const int* __restrict__ flag)
{
  if ((*flag != 0) != F32) return;
  __shared__ __align__(16) u16 ol[128 * 136];
  const u16* WTg = wrep + (size_t)4 * 16384;
  const int t = threadIdx.x;
  const int lane = t & 63;
  const int wid = t >> 6;
  const int n16 = lane & 15;
  const int quad = lane >> 4;
  const int rowBase = blockIdx.x * 128;

  #pragma unroll
  for (int it = 0; it < 8; ++it) {
    const int idx8 = t + it * 256;
    const int r = idx8 >> 4;
    const int c0 = (idx8 & 15) * 8;
    *(us8*)&ol[r * 136 + c0] = *(const us8*)&og[(size_t)(rowBase + r) * CZ + c0];
  }
  __syncthreads();

  f4 acc[2][8];
  #pragma unroll
  for (int i = 0; i < 2; ++i)
    #pragma unroll
    for (int nt = 0; nt < 8; ++nt) acc[i][nt] = f4{0.f, 0.f, 0.f, 0.f};

  #pragma unroll
  for (int ks = 0; ks < 4; ++ks) {
    s8 a[2], b[8];
    #pragma unroll
    for (int i = 0; i < 2; ++i)
      a[i] = *(const s8*)&WTg[ks * 4096 + (((wid * 2 + i) * 4 + quad) * 16 + n16) * 8];
    #pragma unroll
    for (int nt = 0; nt < 8; ++nt)
      b[nt] = *(const s8*)&ol[(nt * 16 + n16) * 136 + ks * 32 + quad * 8];
    #pragma unroll
    for (int i = 0; i < 2; ++i)
      #pragma unroll
      for (int nt = 0; nt < 8; ++nt)
        acc[i][nt] = __builtin_amdgcn_mfma_f32_16x16x32_bf16(a[i], b[nt], acc[i][nt], 0, 0, 0);
  }

  #pragma unroll
  for (int i = 0; i < 2; ++i) {
    const int och0 = (wid * 2 + i) * 16 + quad * 4;
    float b4[4];
    ld4v<F32>(bo, och0, b4);
    #pragma unroll
    for (int nt = 0; nt < 8; ++nt) {
      const size_t off = (size_t)(rowBase + nt * 16 + n16) * CZ + och0;
      if constexpr (F32) {
        float4 o;
        o.x = acc[i][nt][0] + b4[0]; o.y = acc[i][nt][1] + b4[1];
        o.z = acc[i][nt][2] + b4[2]; o.w = acc[i][nt][3] + b4[3];
        *(float4*)&((float*)outp)[off] = o;
      } else {
        us4 o;
        #pragma unroll
        for (int r = 0; r < 4; ++r) o[r] = f2bf(acc[i][nt][r] + b4[r]);
        *(us4*)&((u16*)outp)[off] = o;
      }
    }
  }
}

extern "C" void kernel_launch(void* const* d_in, const int* in_sizes, int n_in,
                              void* d_out, int out_size, void* d_ws, size_t ws_size,
                              hipStream_t stream) {
  const void* z     = d_in[0];
  const void* msk   = d_in[1];
  const void* gma   = d_in[2];
  const void* bta   = d_in[3];
  const void* wbias = d_in[4];
  const void* wq    = d_in[5];
  const void* wk    = d_in[6];
  const void* wv    = d_in[7];
  const void* wg    = d_in[8];
  const void* bg    = d_in[9];
  const void* wo    = d_in[10];
  const void* bo    = d_in[11];

  char* ws = (char*)d_ws;
  int* flag = (int*)ws;
  u16* qb = (u16*)(ws + 256);
  u16* kb = qb + NNCZ;
  u16* vb = kb + NNCZ;
  u16* gb = vb + NNCZ;
  float* triT = (float*)(gb + NNCZ);
  u16* wrep = (u16*)(triT + (size_t)NH * NN);   // 6 * 16384 u16 = 196,608 B
  u16* ogb = qb;  // alias: q slice consumed by the same wave-iteration that writes o

  k_probe<<<dim3(1), dim3(64), 0, stream>>>((const u16*)z, flag);

  k_repack<false><<<dim3(6), dim3(256), 0, stream>>>(wq, wk, wv, wg, wo, wbias, wrep, flag);
  k_repack<true><<<dim3(6), dim3(256), 0, stream>>>(wq, wk, wv, wg, wo, wbias, wrep, flag);

  k_ln_proj<false><<<dim3(NN / 128), dim3(256), 0, stream>>>(
      z, gma, bta, wrep, bg, qb, kb, vb, gb, triT, flag);
  k_ln_proj<true><<<dim3(NN / 128), dim3(256), 0, stream>>>(
      z, gma, bta, wrep, bg, qb, kb, vb, gb, triT, flag);

  k_attn<false><<<dim3(NRES * NH), dim3(256), 0, stream>>>(
      qb, kb, vb, gb, triT, msk, ogb, flag);
  k_attn<true><<<dim3(NRES * NH), dim3(256), 0, stream>>>(
      qb, kb, vb, gb, triT, msk, ogb, flag);

  k_out<false><<<dim3(NN / 128), dim3(256), 0, stream>>>(ogb, wrep, bo, d_out, flag);
  k_out<true><<<dim3(NN / 128), dim3(256), 0, stream>>>(ogb, wrep, bo, d_out, flag);
}

// Round 14
// 438.517 us; speedup vs baseline: 1.2452x; 1.2452x over previous
//
#include <hip/hip_runtime.h>

#define NRES 384
#define CZ 128
#define NH 4
#define CH 32
#define NN (NRES * NRES)
#define NNCZ ((size_t)NN * CZ)

typedef unsigned short u16;
typedef __attribute__((ext_vector_type(4))) unsigned short us4;
typedef __attribute__((ext_vector_type(8))) unsigned short us8;
typedef __attribute__((ext_vector_type(8))) short s8;   // 8 bf16 = MFMA A/B frag
typedef __attribute__((ext_vector_type(4))) float f4;   // MFMA C/D frag

__device__ __forceinline__ float bf2f(u16 u) {
  return __uint_as_float(((unsigned)u) << 16);
}
__device__ __forceinline__ u16 f2bf(float f) {
  unsigned u = __float_as_uint(f);
  u += 0x7fffu + ((u >> 16) & 1u);  // RTNE
  return (u16)(u >> 16);
}

template<bool F32>
__device__ __forceinline__ float ld1(const void* p, size_t i) {
  if constexpr (F32) return ((const float*)p)[i];
  else return bf2f(((const u16*)p)[i]);
}

template<bool F32>
__device__ __forceinline__ void ld4v(const void* p, size_t i, float o[4]) {
  if constexpr (F32) {
    const float4 a = *(const float4*)((const float*)p + i);
    o[0] = a.x; o[1] = a.y; o[2] = a.z; o[3] = a.w;
  } else {
    const us4 v = *(const us4*)((const u16*)p + i);
    #pragma unroll
    for (int u = 0; u < 4; ++u) o[u] = bf2f(v[u]);
  }
}

template<bool F32>
__device__ __forceinline__ void ld8(const void* p, size_t i, float o[8]) {
  if constexpr (F32) {
    const float4 a = *(const float4*)((const float*)p + i);
    const float4 b = *(const float4*)((const float*)p + i + 4);
    o[0] = a.x; o[1] = a.y; o[2] = a.z; o[3] = a.w;
    o[4] = b.x; o[5] = b.y; o[6] = b.z; o[7] = b.w;
  } else {
    const us8 v = *(const us8*)((const u16*)p + i);
    #pragma unroll
    for (int u = 0; u < 8; ++u) o[u] = bf2f(v[u]);
  }
}

// ---------------------------------------------------------------------------
// Probe: decide input dtype from z's exponent-bit statistics.
// ---------------------------------------------------------------------------
__global__ void k_probe(const u16* __restrict__ z, int* __restrict__ flag) {
  int weird = 0;
  for (int i = threadIdx.x; i < 256; i += 64) {
    const int e = (z[i] >> 7) & 0xFF;
    if (e < 0x70 || e > 0x8F) weird++;
  }
  #pragma unroll
  for (int m = 1; m < 64; m <<= 1) weird += __shfl_xor(weird, m, 64);
  if (threadIdx.x == 0) *flag = (weird >= 16) ? 1 : 0;
}

// ---------------------------------------------------------------------------
// K0: one-time weight repack into A-fragment order (bf16, workspace).
//   elem (m=outch, k=c) at [ks*4096 + (((m>>4)*4+qq)*16+(m&15))*8 + j],
//   c = ks*32 + qq*8 + j.
//   Arrays: 0=wq (q-scale folded), 1=wk, 2=wv, 3=wg, 4=wo,
//           5=w_bias padded 4->16 outch (zeros above h=3).
// ---------------------------------------------------------------------------
template<bool F32>
__global__ void k_repack(const void* __restrict__ w0, const void* __restrict__ w1,
                         const void* __restrict__ w2, const void* __restrict__ w3,
                         const void* __restrict__ w4p, const void* __restrict__ w5b,
                         u16* __restrict__ dst, const int* __restrict__ flag) {
  if ((*flag != 0) != F32) return;
  const int a = blockIdx.x;   // 0..5
  u16* d = dst + (size_t)a * 16384;
  const int t = threadIdx.x;
  if (a == 5) {
    #pragma unroll
    for (int it = 0; it < 16; ++it) {
      const int c = (t >> 5) + it * 8;
      const int m0 = (t & 31) * 4;
      float w4[4] = {0.f, 0.f, 0.f, 0.f};
      if (m0 == 0) ld4v<F32>(w5b, (size_t)c * NH, w4);   // wbias[c][0..3]
      const int ks = c >> 5, qq = (c >> 3) & 3, j = c & 7;
      #pragma unroll
      for (int mm = 0; mm < 4; ++mm) {
        const int m = m0 + mm;
        d[ks * 4096 + (((m >> 4) * 4 + qq) * 16 + (m & 15)) * 8 + j] = f2bf(w4[mm]);
      }
    }
    return;
  }
  const void* W = (a == 0) ? w0 : (a == 1) ? w1 : (a == 2) ? w2 : (a == 3) ? w3 : w4p;
  const float scl = (a == 0) ? 0.17677669529663687f : 1.0f;   // CH^-0.5 folded into wq
  #pragma unroll
  for (int it = 0; it < 16; ++it) {
    const int c = (t >> 5) + it * 8;
    const int m0 = (t & 31) * 4;
    float w4[4];
    ld4v<F32>(W, (size_t)c * CZ + m0, w4);
    const int ks = c >> 5, qq = (c >> 3) & 3, j = c & 7;
    #pragma unroll
    for (int mm = 0; mm < 4; ++mm) {
      const int m = m0 + mm;
      d[ks * 4096 + (((m >> 4) * 4 + qq) * 16 + (m & 15)) * 8 + j] = f2bf(w4[mm] * scl);
    }
  }
}

// ---------------------------------------------------------------------------
// K1: LayerNorm + MFMA projections + tri_bias (transposed out).
//   R14 (= R12 revert; R13's (256,3) bound on K1/K3 regressed — 4th
//   launch-bounds poke, 4th regression; allocator near-boundary behavior is
//   adversarial, keep (256,2)). tri_bias via MFMA; q-scale folded into wq.
//   LDS = znl only, 34816 B.
// ---------------------------------------------------------------------------
template<bool F32>
__global__ __launch_bounds__(256, 2) void k_ln_proj(
    const void* __restrict__ z, const void* __restrict__ gma, const void* __restrict__ bta,
    const u16* __restrict__ wrep, const void* __restrict__ bg,
    u16* __restrict__ qb, u16* __restrict__ kb, u16* __restrict__ vb, u16* __restrict__ gb,
    float* __restrict__ triT, const int* __restrict__ flag)
{
  if ((*flag != 0) != F32) return;
  __shared__ __align__(16) u16 znl[128 * 136];   // 34816 B (only LDS)
  const int t = threadIdx.x;
  const int lane = t & 63;
  const int wid = t >> 6;
  const int n16 = lane & 15;
  const int quad = lane >> 4;   // also LN row-group
  const int rowBase = blockIdx.x * 128;

  // ---- LayerNorm ----
  const int c0 = n16 * 8;
  float g8[8], b8[8];
  ld8<F32>(gma, c0, g8);
  ld8<F32>(bta, c0, b8);
  for (int it = 0; it < 8; ++it) {
    const int rl = wid * 32 + it * 4 + quad;
    float x[8];
    ld8<F32>(z, (size_t)(rowBase + rl) * CZ + c0, x);
    float s = 0.f, q2 = 0.f;
    #pragma unroll
    for (int u = 0; u < 8; ++u) { s += x[u]; q2 += x[u] * x[u]; }
    #pragma unroll
    for (int m = 1; m < 16; m <<= 1) {
      s  += __shfl_xor(s, m, 64);
      q2 += __shfl_xor(q2, m, 64);
    }
    const float mu = s * (1.0f / CZ);
    const float rs = rsqrtf(q2 * (1.0f / CZ) - mu * mu + 1e-5f);
    us8 o;
    #pragma unroll
    for (int u = 0; u < 8; ++u) o[u] = f2bf((x[u] - mu) * rs * g8[u] + b8[u]);
    *(us8*)&znl[rl * 136 + c0] = o;
  }
  __syncthreads();

  // ---- tri_bias via MFMA: D = w_bias^T(padded) @ zn^T, rows 0..3 = heads ----
  {
    const u16* WTb = wrep + (size_t)5 * 16384;
    f4 acc2[2];
    acc2[0] = f4{0.f, 0.f, 0.f, 0.f};
    acc2[1] = f4{0.f, 0.f, 0.f, 0.f};
    #pragma unroll
    for (int ks = 0; ks < 4; ++ks) {
      const s8 ab = *(const s8*)&WTb[ks * 4096 + (quad * 16 + n16) * 8];  // mt=0
      #pragma unroll
      for (int i = 0; i < 2; ++i) {
        const s8 b = *(const s8*)&znl[((wid * 2 + i) * 16 + n16) * 136 + ks * 32 + quad * 8];
        acc2[i] = __builtin_amdgcn_mfma_f32_16x16x32_bf16(ab, b, acc2[i], 0, 0, 0);
      }
    }
    if (quad == 0) {
      #pragma unroll
      for (int i = 0; i < 2; ++i) {
        const int P = rowBase + (wid * 2 + i) * 16 + n16;
        const int aI = P / NRES, bI = P % NRES;   // pair (qrow=aI, key=bI)
        #pragma unroll
        for (int r = 0; r < 4; ++r)
          triT[(size_t)r * NN + (size_t)bI * NRES + aI] = acc2[i][r];
      }
    }
  }

  // ---- 4 projection GEMMs, weights from repacked global ----
  for (int arr = 0; arr < 4; ++arr) {
    const u16* WTg = wrep + (size_t)arr * 16384;

    f4 acc[2][8];
    #pragma unroll
    for (int i = 0; i < 2; ++i)
      #pragma unroll
      for (int nt = 0; nt < 8; ++nt) acc[i][nt] = f4{0.f, 0.f, 0.f, 0.f};

    #pragma unroll
    for (int ks = 0; ks < 4; ++ks) {
      s8 a[2], b[8];
      #pragma unroll
      for (int i = 0; i < 2; ++i)
        a[i] = *(const s8*)&WTg[ks * 4096 + (((wid * 2 + i) * 4 + quad) * 16 + n16) * 8];
      #pragma unroll
      for (int nt = 0; nt < 8; ++nt)
        b[nt] = *(const s8*)&znl[(nt * 16 + n16) * 136 + ks * 32 + quad * 8];
      #pragma unroll
      for (int i = 0; i < 2; ++i)
        #pragma unroll
        for (int nt = 0; nt < 8; ++nt)
          acc[i][nt] = __builtin_amdgcn_mfma_f32_16x16x32_bf16(a[i], b[nt], acc[i][nt], 0, 0, 0);
    }

    u16* dstb = (arr == 0) ? qb : (arr == 1) ? kb : (arr == 2) ? vb : gb;
    #pragma unroll
    for (int i = 0; i < 2; ++i) {
      const int mt = wid * 2 + i;
      const int och0 = mt * 16 + quad * 4;
      float e4[4];
      if (arr == 3) ld4v<F32>(bg, och0, e4);
      #pragma unroll
      for (int nt = 0; nt < 8; ++nt) {
        us4 o;
        #pragma unroll
        for (int r = 0; r < 4; ++r) {
          float v = acc[i][nt][r];
          if (arr == 3) v = 1.0f / (1.0f + __expf(-(v + e4[r])));
          o[r] = f2bf(v);
        }
        *(us4*)&dstb[(size_t)(rowBase + nt * 16 + n16) * CZ + och0] = o;
      }
    }
  }
}

// ---------------------------------------------------------------------------
// K2: MFMA attention (exact R4 config — best measured: 206us, 84 VGPR,
// zero spill). Online softmax, 2 q-tiles/wave, 64-key chunks, K reg-prefetch.
// Lesson from R5-R8: live set must stay < ~85 VGPRs or hipcc spills rather
// than allocating more. Do not add register state to this kernel.
//   LDS: 24576 (VB) + 10240 (Pch[4][2]) + 1536 (mbL) = 36352 B.
// ---------------------------------------------------------------------------
template<bool F32>
__global__ __launch_bounds__(256, 3) void k_attn(
    const u16* __restrict__ qb, const u16* __restrict__ kb, const u16* __restrict__ vb,
    const u16* __restrict__ gb, const float* __restrict__ triT, const void* __restrict__ msk,
    u16* __restrict__ ogb, const int* __restrict__ flag)
{
  if ((*flag != 0) != F32) return;
  __shared__ __align__(16) u16 VB[12 * 4 * 32 * 8];  // [sub32][quad][d][j], key-permuted
  __shared__ __align__(16) u16 Pch[4][2][16 * 40];   // per-wave, per-qtile P chunk
  __shared__ __align__(16) float mbL[NRES];          // mask bias per key
  const int t = threadIdx.x;
  const int i = blockIdx.x >> 2;
  const int h = blockIdx.x & 3;
  const size_t base_i = (size_t)i * NRES;

  #pragma unroll
  for (int it = 0; it < 12; ++it) {
    const int idx = t + it * 256;
    const int kk = idx >> 3;
    const int d0 = (idx & 7) * 4;
    const us4 vv = *(const us4*)&vb[(base_i + kk) * CZ + h * CH + d0];
    const int cc2 = kk >> 5;
    const int kap = kk & 31;
    const int p = 2 * (kap & 15) + (kap >> 4);   // key-interleave position
    u16* vdst = &VB[((cc2 * 4 + (p >> 3)) * 32 + d0) * 8 + (p & 7)];
    vdst[0] = vv[0]; vdst[8] = vv[1]; vdst[16] = vv[2]; vdst[24] = vv[3];
  }
  for (int idx = t; idx < NRES; idx += 256)
    mbL[idx] = 1.0e9f * (ld1<F32>(msk, base_i + idx) - 1.0f);
  __syncthreads();

  const int wid = t >> 6;
  const int lane = t & 63;
  const int n = lane & 15;
  const int quad = lane >> 4;
  const float* trih = triT + (size_t)h * NN;
  u16* pbA = &Pch[wid][0][0];
  u16* pbB = &Pch[wid][1][0];

  for (int pr = wid; pr < 12; pr += 4) {
    const int jrowA = pr * 32;
    const int jrowB = jrowA + 16;
    const s8 aqA = *(const s8*)&qb[(base_i + jrowA + n) * CZ + h * CH + quad * 8];
    const s8 aqB = *(const s8*)&qb[(base_i + jrowB + n) * CZ + h * CH + quad * 8];

    f4 O0A = {0.f,0.f,0.f,0.f}, O1A = {0.f,0.f,0.f,0.f};
    f4 O0B = {0.f,0.f,0.f,0.f}, O1B = {0.f,0.f,0.f,0.f};
    f4 lA = {0.f,0.f,0.f,0.f}, lB = {0.f,0.f,0.f,0.f};
    f4 mA = {-1.0e30f,-1.0e30f,-1.0e30f,-1.0e30f};
    f4 mB = {-1.0e30f,-1.0e30f,-1.0e30f,-1.0e30f};

    // preload K chunk 0
    s8 bk[4];
    #pragma unroll
    for (int u = 0; u < 4; ++u)
      bk[u] = *(const s8*)&kb[(base_i + u * 16 + n) * CZ + h * CH + quad * 8];

    #pragma unroll 1
    for (int cc = 0; cc < 6; ++cc) {
      // ---- QK^T for 4 key tiles (64 keys), both q-tiles ----
      f4 SA[4], SB[4];
      #pragma unroll
      for (int u = 0; u < 4; ++u) {
        const f4 z4 = {0.f, 0.f, 0.f, 0.f};
        SA[u] = __builtin_amdgcn_mfma_f32_16x16x32_bf16(aqA, bk[u], z4, 0, 0, 0);
        SB[u] = __builtin_amdgcn_mfma_f32_16x16x32_bf16(aqB, bk[u], z4, 0, 0, 0);
      }
      // ---- prefetch next chunk's K (hidden under softmax+PV) ----
      if (cc < 5) {
        #pragma unroll
        for (int u = 0; u < 4; ++u)
          bk[u] = *(const s8*)&kb[(base_i + ((cc + 1) * 4 + u) * 16 + n) * CZ + h * CH + quad * 8];
      }
      // ---- bias: tri (f32 float4, paired lines) + mask (LDS broadcast) ----
      #pragma unroll
      for (int u = 0; u < 4; ++u) {
        const int tt = cc * 4 + u;
        const float mbv = mbL[tt * 16 + n];
        const size_t trow = (size_t)(tt * 16 + n) * NRES;
        const float4 tA = *(const float4*)&trih[trow + jrowA + quad * 4];
        const float4 tB = *(const float4*)&trih[trow + jrowB + quad * 4];
        SA[u][0] += tA.x + mbv; SA[u][1] += tA.y + mbv;
        SA[u][2] += tA.z + mbv; SA[u][3] += tA.w + mbv;
        SB[u][0] += tB.x + mbv; SB[u][1] += tB.y + mbv;
        SB[u][2] += tB.z + mbv; SB[u][3] += tB.w + mbv;
      }
      // ---- online softmax: chunk max, rescale running state ----
      f4 mxA = SA[0], mxB = SB[0];
      #pragma unroll
      for (int u = 1; u < 4; ++u) {
        #pragma unroll
        for (int r = 0; r < 4; ++r) {
          mxA[r] = fmaxf(mxA[r], SA[u][r]);
          mxB[r] = fmaxf(mxB[r], SB[u][r]);
        }
      }
      #pragma unroll
      for (int sft = 1; sft < 16; sft <<= 1) {
        #pragma unroll
        for (int r = 0; r < 4; ++r) {
          mxA[r] = fmaxf(mxA[r], __shfl_xor(mxA[r], sft, 64));
          mxB[r] = fmaxf(mxB[r], __shfl_xor(mxB[r], sft, 64));
        }
      }
      #pragma unroll
      for (int r = 0; r < 4; ++r) {
        const float mnA = fmaxf(mA[r], mxA[r]);
        const float scA = __expf(mA[r] - mnA);
        mA[r] = mnA;
        O0A[r] *= scA; O1A[r] *= scA; lA[r] *= scA;
        const float mnB = fmaxf(mB[r], mxB[r]);
        const float scB = __expf(mB[r] - mnB);
        mB[r] = mnB;
        O0B[r] *= scB; O1B[r] *= scB; lB[r] *= scB;
      }
      #pragma unroll
      for (int u = 0; u < 4; ++u) {
        #pragma unroll
        for (int r = 0; r < 4; ++r) {
          SA[u][r] = __expf(SA[u][r] - mA[r]);
          lA[r] += SA[u][r];
          SB[u][r] = __expf(SB[u][r] - mB[r]);
          lB[r] += SB[u][r];
        }
      }
      // ---- P pack -> LDS -> PV, 2 sub-chunks of 32 keys; V frags shared ----
      #pragma unroll
      for (int s = 0; s < 2; ++s) {
        #pragma unroll
        for (int r = 0; r < 4; ++r) {
          const unsigned wA = (unsigned)f2bf(SA[2 * s][r]) |
                              ((unsigned)f2bf(SA[2 * s + 1][r]) << 16);
          *(unsigned*)&pbA[(quad * 4 + r) * 40 + n * 2] = wA;
          const unsigned wB = (unsigned)f2bf(SB[2 * s][r]) |
                              ((unsigned)f2bf(SB[2 * s + 1][r]) << 16);
          *(unsigned*)&pbB[(quad * 4 + r) * 40 + n * 2] = wB;
        }
        const int C = cc * 2 + s;
        const s8 apA = *(const s8*)&pbA[n * 40 + quad * 8];
        const s8 apB = *(const s8*)&pbB[n * 40 + quad * 8];
        const s8 bv0 = *(const s8*)&VB[((C * 4 + quad) * 32 + n) * 8];
        const s8 bv1 = *(const s8*)&VB[((C * 4 + quad) * 32 + 16 + n) * 8];
        O0A = __builtin_amdgcn_mfma_f32_16x16x32_bf16(apA, bv0, O0A, 0, 0, 0);
        O1A = __builtin_amdgcn_mfma_f32_16x16x32_bf16(apA, bv1, O1A, 0, 0, 0);
        O0B = __builtin_amdgcn_mfma_f32_16x16x32_bf16(apB, bv0, O0B, 0, 0, 0);
        O1B = __builtin_amdgcn_mfma_f32_16x16x32_bf16(apB, bv1, O1B, 0, 0, 0);
      }
    }

    // ---- finish: sum-reduce over the 16-lane key axis, gate, store ----
    f4 sA = lA, sB = lB;
    #pragma unroll
    for (int sft = 1; sft < 16; sft <<= 1) {
      #pragma unroll
      for (int r = 0; r < 4; ++r) {
        sA[r] += __shfl_xor(sA[r], sft, 64);
        sB[r] += __shfl_xor(sB[r], sft, 64);
      }
    }
    #pragma unroll
    for (int r = 0; r < 4; ++r) {
      const float ivA = 1.0f / sA[r];
      const size_t rowA = (base_i + jrowA + quad * 4 + r) * CZ + h * CH;
      const float gA0 = bf2f(gb[rowA + n]);
      const float gA1 = bf2f(gb[rowA + 16 + n]);
      ogb[rowA + n]      = f2bf(O0A[r] * ivA * gA0);
      ogb[rowA + 16 + n] = f2bf(O1A[r] * ivA * gA1);
      const float ivB = 1.0f / sB[r];
      const size_t rowB = (base_i + jrowB + quad * 4 + r) * CZ + h * CH;
      const float gB0 = bf2f(gb[rowB + n]);
      const float gB1 = bf2f(gb[rowB + 16 + n]);
      ogb[rowB + n]      = f2bf(O0B[r] * ivB * gB0);
      ogb[rowB + 16 + n] = f2bf(O1B[r] * ivB * gB1);
    }
  }
}

// ---------------------------------------------------------------------------
// K3: out = (o*g) @ w_o + b_o.  (R12 config: (256,2))
//   w_o pre-repacked (wrep+4*16384). LDS = ol only 34816 B.
// ---------------------------------------------------------------------------
template<bool F32>
__global__ __launch_bounds__(256, 2) void k_out(
    const u16* __restrict__ og, const u16* __restrict__ wrep, const void* __restrict__ bo,
    void* __restrict__ outp, const int* __restrict__ flag)
{
  if ((*flag != 0) != F32) return;
  __shared__ __align__(16) u16 ol[128 * 136];
  const u16* WTg = wrep + (size_t)4 * 16384;
  const int t = threadIdx.x;
  const int lane = t & 63;
  const int wid = t >> 6;
  const int n16 = lane & 15;
  const int quad = lane >> 4;
  const int rowBase = blockIdx.x * 128;

  #pragma unroll
  for (int it = 0; it < 8; ++it) {
    const int idx8 = t + it * 256;
    const int r = idx8 >> 4;
    const int c0 = (idx8 & 15) * 8;
    *(us8*)&ol[r * 136 + c0] = *(const us8*)&og[(size_t)(rowBase + r) * CZ + c0];
  }
  __syncthreads();

  f4 acc[2][8];
  #pragma unroll
  for (int i = 0; i < 2; ++i)
    #pragma unroll
    for (int nt = 0; nt < 8; ++nt) acc[i][nt] = f4{0.f, 0.f, 0.f, 0.f};

  #pragma unroll
  for (int ks = 0; ks < 4; ++ks) {
    s8 a[2], b[8];
    #pragma unroll
    for (int i = 0; i < 2; ++i)
      a[i] = *(const s8*)&WTg[ks * 4096 + (((wid * 2 + i) * 4 + quad) * 16 + n16) * 8];
    #pragma unroll
    for (int nt = 0; nt < 8; ++nt)
      b[nt] = *(const s8*)&ol[(nt * 16 + n16) * 136 + ks * 32 + quad * 8];
    #pragma unroll
    for (int i = 0; i < 2; ++i)
      #pragma unroll
      for (int nt = 0; nt < 8; ++nt)
        acc[i][nt] = __builtin_amdgcn_mfma_f32_16x16x32_bf16(a[i], b[nt], acc[i][nt], 0, 0, 0);
  }

  #pragma unroll
  for (int i = 0; i < 2; ++i) {
    const int och0 = (wid * 2 + i) * 16 + quad * 4;
    float b4[4];
    ld4v<F32>(bo, och0, b4);
    #pragma unroll
    for (int nt = 0; nt < 8; ++nt) {
      const size_t off = (size_t)(rowBase + nt * 16 + n16) * CZ + och0;
      if constexpr (F32) {
        float4 o;
        o.x = acc[i][nt][0] + b4[0]; o.y = acc[i][nt][1] + b4[1];
        o.z = acc[i][nt][2] + b4[2]; o.w = acc[i][nt][3] + b4[3];
        *(float4*)&((float*)outp)[off] = o;
      } else {
        us4 o;
        #pragma unroll
        for (int r = 0; r < 4; ++r) o[r] = f2bf(acc[i][nt][r] + b4[r]);
        *(us4*)&((u16*)outp)[off] = o;
      }
    }
  }
}

extern "C" void kernel_launch(void* const* d_in, const int* in_sizes, int n_in,
                              void* d_out, int out_size, void* d_ws, size_t ws_size,
                              hipStream_t stream) {
  const void* z     = d_in[0];
  const void* msk   = d_in[1];
  const void* gma   = d_in[2];
  const void* bta   = d_in[3];
  const void* wbias = d_in[4];
  const void* wq    = d_in[5];
  const void* wk    = d_in[6];
  const void* wv    = d_in[7];
  const void* wg    = d_in[8];
  const void* bg    = d_in[9];
  const void* wo    = d_in[10];
  const void* bo    = d_in[11];

  char* ws = (char*)d_ws;
  int* flag = (int*)ws;
  u16* qb = (u16*)(ws + 256);
  u16* kb = qb + NNCZ;
  u16* vb = kb + NNCZ;
  u16* gb = vb + NNCZ;
  float* triT = (float*)(gb + NNCZ);
  u16* wrep = (u16*)(triT + (size_t)NH * NN);   // 6 * 16384 u16 = 196,608 B
  u16* ogb = qb;  // alias: q slice consumed by the same wave-iteration that writes o

  k_probe<<<dim3(1), dim3(64), 0, stream>>>((const u16*)z, flag);

  k_repack<false><<<dim3(6), dim3(256), 0, stream>>>(wq, wk, wv, wg, wo, wbias, wrep, flag);
  k_repack<true><<<dim3(6), dim3(256), 0, stream>>>(wq, wk, wv, wg, wo, wbias, wrep, flag);

  k_ln_proj<false><<<dim3(NN / 128), dim3(256), 0, stream>>>(
      z, gma, bta, wrep, bg, qb, kb, vb, gb, triT, flag);
  k_ln_proj<true><<<dim3(NN / 128), dim3(256), 0, stream>>>(
      z, gma, bta, wrep, bg, qb, kb, vb, gb, triT, flag);

  k_attn<false><<<dim3(NRES * NH), dim3(256), 0, stream>>>(
      qb, kb, vb, gb, triT, msk, ogb, flag);
  k_attn<true><<<dim3(NRES * NH), dim3(256), 0, stream>>>(
      qb, kb, vb, gb, triT, msk, ogb, flag);

  k_out<false><<<dim3(NN / 128), dim3(256), 0, stream>>>(ogb, wrep, bo, d_out, flag);
  k_out<true><<<dim3(NN / 128), dim3(256), 0, stream>>>(ogb, wrep, bo, d_out, flag);
}

// Round 15
// 422.376 us; speedup vs baseline: 1.2928x; 1.0382x over previous
//
#include <hip/hip_runtime.h>

#define NRES 384
#define CZ 128
#define NH 4
#define CH 32
#define NN (NRES * NRES)
#define NNCZ ((size_t)NN * CZ)

typedef unsigned short u16;
typedef __attribute__((ext_vector_type(4))) unsigned short us4;
typedef __attribute__((ext_vector_type(8))) unsigned short us8;
typedef __attribute__((ext_vector_type(8))) short s8;   // 8 bf16 = MFMA A/B frag
typedef __attribute__((ext_vector_type(4))) float f4;   // MFMA C/D frag
typedef __attribute__((ext_vector_type(4))) unsigned ui4;

__device__ __forceinline__ float bf2f(u16 u) {
  return __uint_as_float(((unsigned)u) << 16);
}
__device__ __forceinline__ u16 f2bf(float f) {
  unsigned u = __float_as_uint(f);
  u += 0x7fffu + ((u >> 16) & 1u);  // RTNE
  return (u16)(u >> 16);
}
__device__ __forceinline__ unsigned pk2(float lo, float hi) {
  return (unsigned)f2bf(lo) | ((unsigned)f2bf(hi) << 16);
}

template<bool F32>
__device__ __forceinline__ float ld1(const void* p, size_t i) {
  if constexpr (F32) return ((const float*)p)[i];
  else return bf2f(((const u16*)p)[i]);
}

template<bool F32>
__device__ __forceinline__ void ld4v(const void* p, size_t i, float o[4]) {
  if constexpr (F32) {
    const float4 a = *(const float4*)((const float*)p + i);
    o[0] = a.x; o[1] = a.y; o[2] = a.z; o[3] = a.w;
  } else {
    const us4 v = *(const us4*)((const u16*)p + i);
    #pragma unroll
    for (int u = 0; u < 4; ++u) o[u] = bf2f(v[u]);
  }
}

template<bool F32>
__device__ __forceinline__ void ld8(const void* p, size_t i, float o[8]) {
  if constexpr (F32) {
    const float4 a = *(const float4*)((const float*)p + i);
    const float4 b = *(const float4*)((const float*)p + i + 4);
    o[0] = a.x; o[1] = a.y; o[2] = a.z; o[3] = a.w;
    o[4] = b.x; o[5] = b.y; o[6] = b.z; o[7] = b.w;
  } else {
    const us8 v = *(const us8*)((const u16*)p + i);
    #pragma unroll
    for (int u = 0; u < 8; ++u) o[u] = bf2f(v[u]);
  }
}

// ---------------------------------------------------------------------------
// Probe: decide input dtype from z's exponent-bit statistics.
// ---------------------------------------------------------------------------
__global__ void k_probe(const u16* __restrict__ z, int* __restrict__ flag) {
  int weird = 0;
  for (int i = threadIdx.x; i < 256; i += 64) {
    const int e = (z[i] >> 7) & 0xFF;
    if (e < 0x70 || e > 0x8F) weird++;
  }
  #pragma unroll
  for (int m = 1; m < 64; m <<= 1) weird += __shfl_xor(weird, m, 64);
  if (threadIdx.x == 0) *flag = (weird >= 16) ? 1 : 0;
}

// ---------------------------------------------------------------------------
// K0: one-time weight repack into A-fragment order (bf16, workspace).
//   Arrays: 0=wq (q-scale folded), 1=wk, 2=wv, 3=wg, 4=wo,
//           5=w_bias padded 4->16 outch (zeros above h=3).
// ---------------------------------------------------------------------------
template<bool F32>
__global__ void k_repack(const void* __restrict__ w0, const void* __restrict__ w1,
                         const void* __restrict__ w2, const void* __restrict__ w3,
                         const void* __restrict__ w4p, const void* __restrict__ w5b,
                         u16* __restrict__ dst, const int* __restrict__ flag) {
  if ((*flag != 0) != F32) return;
  const int a = blockIdx.x;   // 0..5
  u16* d = dst + (size_t)a * 16384;
  const int t = threadIdx.x;
  if (a == 5) {
    #pragma unroll
    for (int it = 0; it < 16; ++it) {
      const int c = (t >> 5) + it * 8;
      const int m0 = (t & 31) * 4;
      float w4[4] = {0.f, 0.f, 0.f, 0.f};
      if (m0 == 0) ld4v<F32>(w5b, (size_t)c * NH, w4);   // wbias[c][0..3]
      const int ks = c >> 5, qq = (c >> 3) & 3, j = c & 7;
      #pragma unroll
      for (int mm = 0; mm < 4; ++mm) {
        const int m = m0 + mm;
        d[ks * 4096 + (((m >> 4) * 4 + qq) * 16 + (m & 15)) * 8 + j] = f2bf(w4[mm]);
      }
    }
    return;
  }
  const void* W = (a == 0) ? w0 : (a == 1) ? w1 : (a == 2) ? w2 : (a == 3) ? w3 : w4p;
  const float scl = (a == 0) ? 0.17677669529663687f : 1.0f;   // CH^-0.5 folded into wq
  #pragma unroll
  for (int it = 0; it < 16; ++it) {
    const int c = (t >> 5) + it * 8;
    const int m0 = (t & 31) * 4;
    float w4[4];
    ld4v<F32>(W, (size_t)c * CZ + m0, w4);
    const int ks = c >> 5, qq = (c >> 3) & 3, j = c & 7;
    #pragma unroll
    for (int mm = 0; mm < 4; ++mm) {
      const int m = m0 + mm;
      d[ks * 4096 + (((m >> 4) * 4 + qq) * 16 + (m & 15)) * 8 + j] = f2bf(w4[mm] * scl);
    }
  }
}

// ---------------------------------------------------------------------------
// K1: LayerNorm + MFMA projections + tri_bias.
//   R15: tri stored QROW-MAJOR (tri[h][qrow][key]) for k_attn's swapped-QK
//   float4 bias loads. Otherwise identical to R12/R14.
// ---------------------------------------------------------------------------
template<bool F32>
__global__ __launch_bounds__(256, 2) void k_ln_proj(
    const void* __restrict__ z, const void* __restrict__ gma, const void* __restrict__ bta,
    const u16* __restrict__ wrep, const void* __restrict__ bg,
    u16* __restrict__ qb, u16* __restrict__ kb, u16* __restrict__ vb, u16* __restrict__ gb,
    float* __restrict__ triT, const int* __restrict__ flag)
{
  if ((*flag != 0) != F32) return;
  __shared__ __align__(16) u16 znl[128 * 136];   // 34816 B (only LDS)
  const int t = threadIdx.x;
  const int lane = t & 63;
  const int wid = t >> 6;
  const int n16 = lane & 15;
  const int quad = lane >> 4;   // also LN row-group
  const int rowBase = blockIdx.x * 128;

  // ---- LayerNorm ----
  const int c0 = n16 * 8;
  float g8[8], b8[8];
  ld8<F32>(gma, c0, g8);
  ld8<F32>(bta, c0, b8);
  for (int it = 0; it < 8; ++it) {
    const int rl = wid * 32 + it * 4 + quad;
    float x[8];
    ld8<F32>(z, (size_t)(rowBase + rl) * CZ + c0, x);
    float s = 0.f, q2 = 0.f;
    #pragma unroll
    for (int u = 0; u < 8; ++u) { s += x[u]; q2 += x[u] * x[u]; }
    #pragma unroll
    for (int m = 1; m < 16; m <<= 1) {
      s  += __shfl_xor(s, m, 64);
      q2 += __shfl_xor(q2, m, 64);
    }
    const float mu = s * (1.0f / CZ);
    const float rs = rsqrtf(q2 * (1.0f / CZ) - mu * mu + 1e-5f);
    us8 o;
    #pragma unroll
    for (int u = 0; u < 8; ++u) o[u] = f2bf((x[u] - mu) * rs * g8[u] + b8[u]);
    *(us8*)&znl[rl * 136 + c0] = o;
  }
  __syncthreads();

  // ---- tri_bias via MFMA: rows 0..3 of D = heads; store qrow-major ----
  {
    const u16* WTb = wrep + (size_t)5 * 16384;
    f4 acc2[2];
    acc2[0] = f4{0.f, 0.f, 0.f, 0.f};
    acc2[1] = f4{0.f, 0.f, 0.f, 0.f};
    #pragma unroll
    for (int ks = 0; ks < 4; ++ks) {
      const s8 ab = *(const s8*)&WTb[ks * 4096 + (quad * 16 + n16) * 8];  // mt=0
      #pragma unroll
      for (int i = 0; i < 2; ++i) {
        const s8 b = *(const s8*)&znl[((wid * 2 + i) * 16 + n16) * 136 + ks * 32 + quad * 8];
        acc2[i] = __builtin_amdgcn_mfma_f32_16x16x32_bf16(ab, b, acc2[i], 0, 0, 0);
      }
    }
    if (quad == 0) {
      #pragma unroll
      for (int i = 0; i < 2; ++i) {
        const int P = rowBase + (wid * 2 + i) * 16 + n16;
        const int aI = P / NRES, bI = P % NRES;   // pair (qrow=aI, key=bI)
        #pragma unroll
        for (int r = 0; r < 4; ++r)
          triT[(size_t)r * NN + (size_t)aI * NRES + bI] = acc2[i][r];
      }
    }
  }

  // ---- 4 projection GEMMs, weights from repacked global ----
  for (int arr = 0; arr < 4; ++arr) {
    const u16* WTg = wrep + (size_t)arr * 16384;

    f4 acc[2][8];
    #pragma unroll
    for (int i = 0; i < 2; ++i)
      #pragma unroll
      for (int nt = 0; nt < 8; ++nt) acc[i][nt] = f4{0.f, 0.f, 0.f, 0.f};

    #pragma unroll
    for (int ks = 0; ks < 4; ++ks) {
      s8 a[2], b[8];
      #pragma unroll
      for (int i = 0; i < 2; ++i)
        a[i] = *(const s8*)&WTg[ks * 4096 + (((wid * 2 + i) * 4 + quad) * 16 + n16) * 8];
      #pragma unroll
      for (int nt = 0; nt < 8; ++nt)
        b[nt] = *(const s8*)&znl[(nt * 16 + n16) * 136 + ks * 32 + quad * 8];
      #pragma unroll
      for (int i = 0; i < 2; ++i)
        #pragma unroll
        for (int nt = 0; nt < 8; ++nt)
          acc[i][nt] = __builtin_amdgcn_mfma_f32_16x16x32_bf16(a[i], b[nt], acc[i][nt], 0, 0, 0);
    }

    u16* dstb = (arr == 0) ? qb : (arr == 1) ? kb : (arr == 2) ? vb : gb;
    #pragma unroll
    for (int i = 0; i < 2; ++i) {
      const int mt = wid * 2 + i;
      const int och0 = mt * 16 + quad * 4;
      float e4[4];
      if (arr == 3) ld4v<F32>(bg, och0, e4);
      #pragma unroll
      for (int nt = 0; nt < 8; ++nt) {
        us4 o;
        #pragma unroll
        for (int r = 0; r < 4; ++r) {
          float v = acc[i][nt][r];
          if (arr == 3) v = 1.0f / (1.0f + __expf(-(v + e4[r])));
          o[r] = f2bf(v);
        }
        *(us4*)&dstb[(size_t)(rowBase + nt * 16 + n16) * CZ + och0] = o;
      }
    }
  }
}

// ---------------------------------------------------------------------------
// K2: MFMA attention, SWAPPED-QK form: S = mfma(K, Q) so S[key=quad*4+r]
//   [qrow=n] — softmax rows lane-local (in-lane reduce + 2 shuffles),
//   P->A-frag via 8 shfl + 4 selects (NO Pch LDS), V natural key order.
//   LDS: 24576 (VB) + 1536 (mbL) = 26112 B -> 6 blocks/CU, whole grid
//   (1536 = 256x6) resident, tail gone. O layout/stores unchanged.
// ---------------------------------------------------------------------------
template<bool F32>
__global__ __launch_bounds__(256, 3) void k_attn(
    const u16* __restrict__ qb, const u16* __restrict__ kb, const u16* __restrict__ vb,
    const u16* __restrict__ gb, const float* __restrict__ triT, const void* __restrict__ msk,
    u16* __restrict__ ogb, const int* __restrict__ flag)
{
  if ((*flag != 0) != F32) return;
  __shared__ __align__(16) u16 VB[12 * 4 * 32 * 8];  // [chunk32][grp8][d][j], natural order
  __shared__ __align__(16) float mbL[NRES];          // mask bias per key
  const int t = threadIdx.x;
  const int i = blockIdx.x >> 2;
  const int h = blockIdx.x & 3;
  const size_t base_i = (size_t)i * NRES;

  #pragma unroll
  for (int it = 0; it < 12; ++it) {
    const int idx = t + it * 256;
    const int kk = idx >> 3;
    const int d0 = (idx & 7) * 4;
    const us4 vv = *(const us4*)&vb[(base_i + kk) * CZ + h * CH + d0];
    const int cc2 = kk >> 5;
    const int kap = kk & 31;
    u16* vdst = &VB[((cc2 * 4 + (kap >> 3)) * 32 + d0) * 8 + (kap & 7)];
    vdst[0] = vv[0]; vdst[8] = vv[1]; vdst[16] = vv[2]; vdst[24] = vv[3];
  }
  for (int idx = t; idx < NRES; idx += 256)
    mbL[idx] = 1.0e9f * (ld1<F32>(msk, base_i + idx) - 1.0f);
  __syncthreads();

  const int wid = t >> 6;
  const int lane = t & 63;
  const int n = lane & 15;
  const int quad = lane >> 4;
  const float* trih = triT + (size_t)h * NN;   // [qrow][key]
  const int src0 = n + ((quad & 1) << 5);      // cross-quad exchange sources
  const int src1 = src0 + 16;
  const bool hiq = quad >= 2;

  for (int pr = wid; pr < 12; pr += 4) {
    const int jrowA = pr * 32;
    const int jrowB = jrowA + 16;
    const s8 aqA = *(const s8*)&qb[(base_i + jrowA + n) * CZ + h * CH + quad * 8];
    const s8 aqB = *(const s8*)&qb[(base_i + jrowB + n) * CZ + h * CH + quad * 8];

    f4 O0A = {0.f,0.f,0.f,0.f}, O1A = {0.f,0.f,0.f,0.f};
    f4 O0B = {0.f,0.f,0.f,0.f}, O1B = {0.f,0.f,0.f,0.f};
    float lA = 0.f, lB = 0.f;
    float mA = -1.0e30f, mB = -1.0e30f;

    // preload K chunk 0
    s8 bk[4];
    #pragma unroll
    for (int u = 0; u < 4; ++u)
      bk[u] = *(const s8*)&kb[(base_i + u * 16 + n) * CZ + h * CH + quad * 8];

    #pragma unroll 1
    for (int cc = 0; cc < 6; ++cc) {
      // ---- QK^T (swapped): S[key=quad*4+r][qrow=n] ----
      f4 SA[4], SB[4];
      #pragma unroll
      for (int u = 0; u < 4; ++u) {
        const f4 z4 = {0.f, 0.f, 0.f, 0.f};
        SA[u] = __builtin_amdgcn_mfma_f32_16x16x32_bf16(bk[u], aqA, z4, 0, 0, 0);
        SB[u] = __builtin_amdgcn_mfma_f32_16x16x32_bf16(bk[u], aqB, z4, 0, 0, 0);
      }
      // ---- prefetch next chunk's K ----
      if (cc < 5) {
        #pragma unroll
        for (int u = 0; u < 4; ++u)
          bk[u] = *(const s8*)&kb[(base_i + ((cc + 1) * 4 + u) * 16 + n) * CZ + h * CH + quad * 8];
      }
      // ---- bias: tri qrow-major float4 + mask float4 (both key-contig) ----
      #pragma unroll
      for (int u = 0; u < 4; ++u) {
        const int kb0 = (cc * 4 + u) * 16 + quad * 4;
        const float4 mb4 = *(const float4*)&mbL[kb0];
        const float4 tA = *(const float4*)&trih[(size_t)(jrowA + n) * NRES + kb0];
        const float4 tB = *(const float4*)&trih[(size_t)(jrowB + n) * NRES + kb0];
        SA[u][0] += tA.x + mb4.x; SA[u][1] += tA.y + mb4.y;
        SA[u][2] += tA.z + mb4.z; SA[u][3] += tA.w + mb4.w;
        SB[u][0] += tB.x + mb4.x; SB[u][1] += tB.y + mb4.y;
        SB[u][2] += tB.z + mb4.z; SB[u][3] += tB.w + mb4.w;
      }
      // ---- chunk max: in-lane 16 + cross-quad (2 shuffles) ----
      float mxA = fmaxf(fmaxf(SA[0][0], SA[0][1]), fmaxf(SA[0][2], SA[0][3]));
      float mxB = fmaxf(fmaxf(SB[0][0], SB[0][1]), fmaxf(SB[0][2], SB[0][3]));
      #pragma unroll
      for (int u = 1; u < 4; ++u) {
        mxA = fmaxf(mxA, fmaxf(fmaxf(SA[u][0], SA[u][1]), fmaxf(SA[u][2], SA[u][3])));
        mxB = fmaxf(mxB, fmaxf(fmaxf(SB[u][0], SB[u][1]), fmaxf(SB[u][2], SB[u][3])));
      }
      mxA = fmaxf(mxA, __shfl_xor(mxA, 16, 64));
      mxA = fmaxf(mxA, __shfl_xor(mxA, 32, 64));
      mxB = fmaxf(mxB, __shfl_xor(mxB, 16, 64));
      mxB = fmaxf(mxB, __shfl_xor(mxB, 32, 64));
      // ---- rescale running state ----
      const float mnA = fmaxf(mA, mxA);
      const float scA = __expf(mA - mnA);
      mA = mnA; lA *= scA;
      const float mnB = fmaxf(mB, mxB);
      const float scB = __expf(mB - mnB);
      mB = mnB; lB *= scB;
      #pragma unroll
      for (int r = 0; r < 4; ++r) {
        const float srA = __shfl(scA, quad * 4 + r, 16);
        O0A[r] *= srA; O1A[r] *= srA;
        const float srB = __shfl(scB, quad * 4 + r, 16);
        O0B[r] *= srB; O1B[r] *= srB;
      }
      // ---- exp + partial l (in-lane; qrow = n) ----
      #pragma unroll
      for (int u = 0; u < 4; ++u) {
        #pragma unroll
        for (int r = 0; r < 4; ++r) {
          SA[u][r] = __expf(SA[u][r] - mA);
          lA += SA[u][r];
          SB[u][r] = __expf(SB[u][r] - mB);
          lB += SB[u][r];
        }
      }
      // ---- P exchange (pack + 8 shfl + 4 sel) -> PV, per 32-key sub-chunk ----
      #pragma unroll
      for (int s = 0; s < 2; ++s) {
        const int C = cc * 2 + s;
        const s8 bv0 = *(const s8*)&VB[((C * 4 + quad) * 32 + n) * 8];
        const s8 bv1 = *(const s8*)&VB[((C * 4 + quad) * 32 + 16 + n) * 8];
        {
          const unsigned lo0 = pk2(SA[2*s][0], SA[2*s][1]);
          const unsigned lo1 = pk2(SA[2*s][2], SA[2*s][3]);
          const unsigned hi0 = pk2(SA[2*s+1][0], SA[2*s+1][1]);
          const unsigned hi1 = pk2(SA[2*s+1][2], SA[2*s+1][3]);
          const unsigned x0l = __shfl(lo0, src0, 64), x0h = __shfl(hi0, src0, 64);
          const unsigned x1l = __shfl(lo1, src0, 64), x1h = __shfl(hi1, src0, 64);
          const unsigned x2l = __shfl(lo0, src1, 64), x2h = __shfl(hi0, src1, 64);
          const unsigned x3l = __shfl(lo1, src1, 64), x3h = __shfl(hi1, src1, 64);
          const ui4 W = { hiq ? x0h : x0l, hiq ? x1h : x1l,
                          hiq ? x2h : x2l, hiq ? x3h : x3l };
          const s8 apA = __builtin_bit_cast(s8, W);
          O0A = __builtin_amdgcn_mfma_f32_16x16x32_bf16(apA, bv0, O0A, 0, 0, 0);
          O1A = __builtin_amdgcn_mfma_f32_16x16x32_bf16(apA, bv1, O1A, 0, 0, 0);
        }
        {
          const unsigned lo0 = pk2(SB[2*s][0], SB[2*s][1]);
          const unsigned lo1 = pk2(SB[2*s][2], SB[2*s][3]);
          const unsigned hi0 = pk2(SB[2*s+1][0], SB[2*s+1][1]);
          const unsigned hi1 = pk2(SB[2*s+1][2], SB[2*s+1][3]);
          const unsigned x0l = __shfl(lo0, src0, 64), x0h = __shfl(hi0, src0, 64);
          const unsigned x1l = __shfl(lo1, src0, 64), x1h = __shfl(hi1, src0, 64);
          const unsigned x2l = __shfl(lo0, src1, 64), x2h = __shfl(hi0, src1, 64);
          const unsigned x3l = __shfl(lo1, src1, 64), x3h = __shfl(hi1, src1, 64);
          const ui4 W = { hiq ? x0h : x0l, hiq ? x1h : x1l,
                          hiq ? x2h : x2l, hiq ? x3h : x3l };
          const s8 apB = __builtin_bit_cast(s8, W);
          O0B = __builtin_amdgcn_mfma_f32_16x16x32_bf16(apB, bv0, O0B, 0, 0, 0);
          O1B = __builtin_amdgcn_mfma_f32_16x16x32_bf16(apB, bv1, O1B, 0, 0, 0);
        }
      }
    }

    // ---- finish: cross-quad sum (2 shuffles), distribute, gate, store ----
    float sA = lA, sB = lB;
    sA += __shfl_xor(sA, 16, 64); sA += __shfl_xor(sA, 32, 64);
    sB += __shfl_xor(sB, 16, 64); sB += __shfl_xor(sB, 32, 64);
    #pragma unroll
    for (int r = 0; r < 4; ++r) {
      const float ivA = 1.0f / __shfl(sA, quad * 4 + r, 16);
      const size_t rowA = (base_i + jrowA + quad * 4 + r) * CZ + h * CH;
      const float gA0 = bf2f(gb[rowA + n]);
      const float gA1 = bf2f(gb[rowA + 16 + n]);
      ogb[rowA + n]      = f2bf(O0A[r] * ivA * gA0);
      ogb[rowA + 16 + n] = f2bf(O1A[r] * ivA * gA1);
      const float ivB = 1.0f / __shfl(sB, quad * 4 + r, 16);
      const size_t rowB = (base_i + jrowB + quad * 4 + r) * CZ + h * CH;
      const float gB0 = bf2f(gb[rowB + n]);
      const float gB1 = bf2f(gb[rowB + 16 + n]);
      ogb[rowB + n]      = f2bf(O0B[r] * ivB * gB0);
      ogb[rowB + 16 + n] = f2bf(O1B[r] * ivB * gB1);
    }
  }
}

// ---------------------------------------------------------------------------
// K3: out = (o*g) @ w_o + b_o.  (unchanged; R12 config (256,2))
// ---------------------------------------------------------------------------
template<bool F32>
__global__ __launch_bounds__(256, 2) void k_out(
    const u16* __restrict__ og, const u16* __restrict__ wrep, const void* __restrict__ bo,
    void* __restrict__ outp, const int* __restrict__ flag)
{
  if ((*flag != 0) != F32) return;
  __shared__ __align__(16) u16 ol[128 * 136];
  const u16* WTg = wrep + (size_t)4 * 16384;
  const int t = threadIdx.x;
  const int lane = t & 63;
  const int wid = t >> 6;
  const int n16 = lane & 15;
  const int quad = lane >> 4;
  const int rowBase = blockIdx.x * 128;

  #pragma unroll
  for (int it = 0; it < 8; ++it) {
    const int idx8 = t + it * 256;
    const int r = idx8 >> 4;
    const int c0 = (idx8 & 15) * 8;
    *(us8*)&ol[r * 136 + c0] = *(const us8*)&og[(size_t)(rowBase + r) * CZ + c0];
  }
  __syncthreads();

  f4 acc[2][8];
  #pragma unroll
  for (int i = 0; i < 2; ++i)
    #pragma unroll
    for (int nt = 0; nt < 8; ++nt) acc[i][nt] = f4{0.f, 0.f, 0.f, 0.f};

  #pragma unroll
  for (int ks = 0; ks < 4; ++ks) {
    s8 a[2], b[8];
    #pragma unroll
    for (int i = 0; i < 2; ++i)
      a[i] = *(const s8*)&WTg[ks * 4096 + (((wid * 2 + i) * 4 + quad) * 16 + n16) * 8];
    #pragma unroll
    for (int nt = 0; nt < 8; ++nt)
      b[nt] = *(const s8*)&ol[(nt * 16 + n16) * 136 + ks * 32 + quad * 8];
    #pragma unroll
    for (int i = 0; i < 2; ++i)
      #pragma unroll
      for (int nt = 0; nt < 8; ++nt)
        acc[i][nt] = __builtin_amdgcn_mfma_f32_16x16x32_bf16(a[i], b[nt], acc[i][nt], 0, 0, 0);
  }

  #pragma unroll
  for (int i = 0; i < 2; ++i) {
    const int och0 = (wid * 2 + i) * 16 + quad * 4;
    float b4[4];
    ld4v<F32>(bo, och0, b4);
    #pragma unroll
    for (int nt = 0; nt < 8; ++nt) {
      const size_t off = (size_t)(rowBase + nt * 16 + n16) * CZ + och0;
      if constexpr (F32) {
        float4 o;
        o.x = acc[i][nt][0] + b4[0]; o.y = acc[i][nt][1] + b4[1];
        o.z = acc[i][nt][2] + b4[2]; o.w = acc[i][nt][3] + b4[3];
        *(float4*)&((float*)outp)[off] = o;
      } else {
        us4 o;
        #pragma unroll
        for (int r = 0; r < 4; ++r) o[r] = f2bf(acc[i][nt][r] + b4[r]);
        *(us4*)&((u16*)outp)[off] = o;
      }
    }
  }
}

extern "C" void kernel_launch(void* const* d_in, const int* in_sizes, int n_in,
                              void* d_out, int out_size, void* d_ws, size_t ws_size,
                              hipStream_t stream) {
  const void* z     = d_in[0];
  const void* msk   = d_in[1];
  const void* gma   = d_in[2];
  const void* bta   = d_in[3];
  const void* wbias = d_in[4];
  const void* wq    = d_in[5];
  const void* wk    = d_in[6];
  const void* wv    = d_in[7];
  const void* wg    = d_in[8];
  const void* bg    = d_in[9];
  const void* wo    = d_in[10];
  const void* bo    = d_in[11];

  char* ws = (char*)d_ws;
  int* flag = (int*)ws;
  u16* qb = (u16*)(ws + 256);
  u16* kb = qb + NNCZ;
  u16* vb = kb + NNCZ;
  u16* gb = vb + NNCZ;
  float* triT = (float*)(gb + NNCZ);
  u16* wrep = (u16*)(triT + (size_t)NH * NN);   // 6 * 16384 u16 = 196,608 B
  u16* ogb = qb;  // alias: q slice consumed by the same wave-iteration that writes o

  k_probe<<<dim3(1), dim3(64), 0, stream>>>((const u16*)z, flag);

  k_repack<false><<<dim3(6), dim3(256), 0, stream>>>(wq, wk, wv, wg, wo, wbias, wrep, flag);
  k_repack<true><<<dim3(6), dim3(256), 0, stream>>>(wq, wk, wv, wg, wo, wbias, wrep, flag);

  k_ln_proj<false><<<dim3(NN / 128), dim3(256), 0, stream>>>(
      z, gma, bta, wrep, bg, qb, kb, vb, gb, triT, flag);
  k_ln_proj<true><<<dim3(NN / 128), dim3(256), 0, stream>>>(
      z, gma, bta, wrep, bg, qb, kb, vb, gb, triT, flag);

  k_attn<false><<<dim3(NRES * NH), dim3(256), 0, stream>>>(
      qb, kb, vb, gb, triT, msk, ogb, flag);
  k_attn<true><<<dim3(NRES * NH), dim3(256), 0, stream>>>(
      qb, kb, vb, gb, triT, msk, ogb, flag);

  k_out<false><<<dim3(NN / 128), dim3(256), 0, stream>>>(ogb, wrep, bo, d_out, flag);
  k_out<true><<<dim3(NN / 128), dim3(256), 0, stream>>>(ogb, wrep, bo, d_out, flag);
}